// Round 4
// baseline (97.368 us; speedup 1.0000x reference)
//
#include <hip/hip_runtime.h>
#include <hip/hip_bf16.h>

#define B_   32
#define L_   2048
#define DIN  384
#define DH   64
#define DOUT 64
#define CS   32      // chunk length
#define NC   64      // chunks per sequence
#define WN   192     // Z row: shorts [0..127]=(re,im) pairs h=0..63; [128..191]=(Du_c,Du_{c+32}) pairs c=0..31

typedef __attribute__((ext_vector_type(8)))  short short8;
typedef __attribute__((ext_vector_type(4)))  float f32x4;
typedef __attribute__((ext_vector_type(16))) float f32x16;

__device__ __forceinline__ float bf2f(short s) {
  union { unsigned u; float f; } cv;
  cv.u = ((unsigned)(unsigned short)s) << 16;
  return cv.f;
}
__device__ __forceinline__ short f2bf(float f) {
  __hip_bfloat16 h = __float2bfloat16(f);
  union { __hip_bfloat16 h; short s; } cv; cv.h = h;
  return cv.s;
}
__device__ __forceinline__ unsigned pack2(float lo, float hi) {
  return (unsigned)(unsigned short)f2bf(lo) | ((unsigned)(unsigned short)f2bf(hi) << 16);
}

// ---------------- K0: pack Wp (B-frag order), Ctp (proj B-frag order), lamtab ----
__global__ void k0_prep(const float* __restrict__ nu_log, const float* __restrict__ theta_log,
                        const float* __restrict__ gamma_log,
                        const float* __restrict__ B_re, const float* __restrict__ B_im,
                        const float* __restrict__ C_re, const float* __restrict__ C_im,
                        const float* __restrict__ Dm,
                        short* __restrict__ Wp, short* __restrict__ Ctp,
                        float* __restrict__ lamtab) {
  int tid = blockIdx.x * 256 + threadIdx.x;
  // Wp[((nt*24+ks)*64+l)*8+j] = W[nt*32+(l&31)][ks*16+(l>>5)*8+j]
  for (int q = tid; q < 6 * 24 * 64; q += gridDim.x * 256) {
    int l = q & 63, ks = (q >> 6) % 24, nt = q / (24 * 64);
    int n = nt * 32 + (l & 31);
    int k0 = ks * 16 + ((l >> 5) << 3);
    short8 v;
    #pragma unroll
    for (int j = 0; j < 8; ++j) {
      int k = k0 + j;
      float x;
      if (n < 64)       x = B_re[n * DIN + k] * expf(gamma_log[n]);
      else if (n < 128) x = B_im[(n - 64) * DIN + k] * expf(gamma_log[n - 64]);
      else              x = Dm[(n - 128) * DIN + k];
      v[j] = f2bf(x);
    }
    *(short8*)(Wp + (size_t)q * 8) = v;
  }
  // Ctp[((nt2*8+ks2)*64+l)*8+j]: B[k][o], k<64 -> C_re[o][k], k>=64 -> -C_im[o][k-64]
  for (int q = tid; q < 2 * 8 * 64; q += gridDim.x * 256) {
    int l = q & 63, ks2 = (q >> 6) & 7, nt2 = q >> 9;
    int o = nt2 * 32 + (l & 31);
    int kk0 = ks2 * 16 + ((l >> 5) << 3);
    short8 v;
    #pragma unroll
    for (int j = 0; j < 8; ++j) {
      int k = kk0 + j;
      float x = (k < 64) ? C_re[o * DH + k] : -C_im[o * DH + (k - 64)];
      v[j] = f2bf(x);
    }
    *(short8*)(Ctp + (size_t)q * 8) = v;
  }
  if (blockIdx.x == 0 && threadIdx.x < 64) {
    int h = threadIdx.x;
    float nu = expf(nu_log[h]);
    float th = expf(theta_log[h]);
    float rr = expf(-nu);
    float lr = rr * cosf(th), li = rr * sinf(th);
    float ar = lr, ai = li;
    #pragma unroll
    for (int q = 0; q < 5; ++q) { float nr = ar * ar - ai * ai; ai = 2.f * ar * ai; ar = nr; }
    lamtab[h] = lr; lamtab[64 + h] = li;        // lambda
    lamtab[128 + h] = ar; lamtab[192 + h] = ai; // lambda^32
  }
}

// ---- K1: LDS-staged GEMM (32x32x16 MFMA), scratch-proof, + in-register chunk scan ----
__global__ __launch_bounds__(128, 2) void k1_gemm_scan(const float* __restrict__ X,
                                                       const short* __restrict__ Wp,
                                                       const float* __restrict__ lamtab,
                                                       short* __restrict__ Z,
                                                       float* __restrict__ E) {
  __shared__ short Xs[64 * 384];                 // 48 KB, XOR-swizzled on 8-elem units
  const int t = threadIdx.x, w = t >> 6, lane = t & 63;
  const int m0 = blockIdx.x * 64;

  // ---- stage X tile: fp32 -> bf16 -> swizzled LDS (coalesced global reads)
  #pragma unroll 6
  for (int it = 0; it < 24; ++it) {
    int q8 = it * 128 + t;                       // 8-elem unit id, 0..3071
    int r = q8 / 48, u = q8 - r * 48;
    const float* src = X + (size_t)(m0 + r) * DIN + u * 8;
    f32x4 a0 = *(const f32x4*)src;
    f32x4 a1 = *(const f32x4*)(src + 4);
    short8 v;
    #pragma unroll
    for (int i = 0; i < 4; ++i) { v[i] = f2bf(a0[i]); v[4 + i] = f2bf(a1[i]); }
    int up = (u & ~7) | ((u ^ r) & 7);
    *(short8*)&Xs[r * 384 + up * 8] = v;
  }
  __syncthreads();

  const int c = lane & 31, kh = lane >> 5;
  const int rr = w * 32 + c;                     // row within tile (= chunk row)
  const short* xrow = &Xs[rr * 384];
  const short* wq = Wp + (size_t)lane * 8;

  f32x16 acc0, acc1, acc2, acc3, acc4, acc5;
  #pragma unroll
  for (int j = 0; j < 16; ++j) {
    acc0[j] = 0.f; acc1[j] = 0.f; acc2[j] = 0.f;
    acc3[j] = 0.f; acc4[j] = 0.f; acc5[j] = 0.f;
  }

#define AREAD(KS) (*(const short8*)&xrow[(((((KS)*2 + kh)) & ~7) | ((((KS)*2 + kh) ^ rr) & 7)) * 8])

  short8 a_c = AREAD(0);
  short8 b0 = *(const short8*)(wq + 0 * 12288 + 0 * 512);
  short8 b1 = *(const short8*)(wq + 1 * 12288 + 0 * 512);
  short8 b2 = *(const short8*)(wq + 2 * 12288 + 0 * 512);
  short8 b3 = *(const short8*)(wq + 3 * 12288 + 0 * 512);
  short8 b4 = *(const short8*)(wq + 4 * 12288 + 0 * 512);
  short8 b5 = *(const short8*)(wq + 5 * 12288 + 0 * 512);

  #pragma unroll
  for (int ks = 0; ks < 24; ++ks) {
    short8 a_n, n0, n1, n2, n3, n4, n5;
    if (ks < 23) {
      a_n = AREAD(ks + 1);
      n0 = *(const short8*)(wq + 0 * 12288 + (ks + 1) * 512);
      n1 = *(const short8*)(wq + 1 * 12288 + (ks + 1) * 512);
      n2 = *(const short8*)(wq + 2 * 12288 + (ks + 1) * 512);
      n3 = *(const short8*)(wq + 3 * 12288 + (ks + 1) * 512);
      n4 = *(const short8*)(wq + 4 * 12288 + (ks + 1) * 512);
      n5 = *(const short8*)(wq + 5 * 12288 + (ks + 1) * 512);
    }
    acc0 = __builtin_amdgcn_mfma_f32_32x32x16_bf16(a_c, b0, acc0, 0, 0, 0);
    acc1 = __builtin_amdgcn_mfma_f32_32x32x16_bf16(a_c, b1, acc1, 0, 0, 0);
    acc2 = __builtin_amdgcn_mfma_f32_32x32x16_bf16(a_c, b2, acc2, 0, 0, 0);
    acc3 = __builtin_amdgcn_mfma_f32_32x32x16_bf16(a_c, b3, acc3, 0, 0, 0);
    acc4 = __builtin_amdgcn_mfma_f32_32x32x16_bf16(a_c, b4, acc4, 0, 0, 0);
    acc5 = __builtin_amdgcn_mfma_f32_32x32x16_bf16(a_c, b5, acc5, 0, 0, 0);
    if (ks < 23) {
      a_c = a_n;
      b0 = n0; b1 = n1; b2 = n2; b3 = n3; b4 = n4; b5 = n5;
    }
  }
#undef AREAD

  // ---- in-register local scan over 32 rows; h1=c (acc0/acc2), h2=32+c (acc1/acc3)
  const float lr1 = lamtab[c],      li1 = lamtab[64 + c];
  const float lr2 = lamtab[32 + c], li2 = lamtab[96 + c];
  float sr1 = 0.f, si1 = 0.f, sr2 = 0.f, si2 = 0.f;
  #pragma unroll
  for (int g = 0; g < 8; ++g) {
    const int active = (g & 1);
    if (kh == active) {
      #pragma unroll
      for (int j = 0; j < 4; ++j) {
        const int r = 4 * (g >> 1) + j;
        float nr1 = lr1 * sr1 - li1 * si1 + acc0[r];
        si1 = lr1 * si1 + li1 * sr1 + acc2[r];
        sr1 = nr1;
        acc0[r] = sr1; acc2[r] = si1;
        float nr2 = lr2 * sr2 - li2 * si2 + acc1[r];
        si2 = lr2 * si2 + li2 * sr2 + acc3[r];
        sr2 = nr2;
        acc1[r] = sr2; acc3[r] = si2;
      }
    }
    float tr1 = __shfl_xor(sr1, 32), ti1 = __shfl_xor(si1, 32);
    float tr2 = __shfl_xor(sr2, 32), ti2 = __shfl_xor(si2, 32);
    if (kh != active) { sr1 = tr1; si1 = ti1; sr2 = tr2; si2 = ti2; }
  }

  // ---- store Z (paired bf16 dwords): (re,im) for h=c and h=32+c, (Du_c,Du_{c+32})
  const int mrow = m0 + w * 32;
  #pragma unroll
  for (int reg = 0; reg < 16; ++reg) {
    const int row = (reg & 3) + 8 * (reg >> 2) + 4 * kh;
    short* zr = Z + (size_t)(mrow + row) * WN;
    *(unsigned*)(zr + 2 * c)       = pack2(acc0[reg], acc2[reg]);   // h = c
    *(unsigned*)(zr + 64 + 2 * c)  = pack2(acc1[reg], acc3[reg]);   // h = 32+c
    *(unsigned*)(zr + 128 + 2 * c) = pack2(acc4[reg], acc5[reg]);   // Du c, 32+c
  }
  if (kh == 0) {
    float* Ep = E + (size_t)(blockIdx.x * 2 + w) * 128;
    Ep[c] = sr1;       Ep[64 + c] = si1;
    Ep[32 + c] = sr2;  Ep[96 + c] = si2;
  }
}

// ---- K4: carry + correction + MFMA projection + Du + chunk max ----
__global__ __launch_bounds__(256, 2) void k4_scanproj(const short* __restrict__ Z,
                                                      const float* __restrict__ lamtab,
                                                      const float* __restrict__ E,
                                                      const short* __restrict__ Ctp,
                                                      float* __restrict__ P) {
  const int t = threadIdx.x, w = t >> 6, lane = t & 63;
  const int b = blockIdx.x >> 4, cg = blockIdx.x & 15;
  const int c = cg * 4 + w;                      // this wave's chunk
  __shared__ short Zs[4][CS * WN];               // 48 KB
  __shared__ short xsA[4][CS * 128];             // 32 KB, swizzled A-frag layout

  const size_t zbase = (size_t)(b * L_ + cg * 128) * WN;   // 4 consecutive chunks
  #pragma unroll
  for (int it = 0; it < 12; ++it) {
    int q = it * 256 + t;                        // short8 units, 0..3071
    ((short8*)Zs)[q] = *(const short8*)(Z + zbase + (size_t)q * 8);
  }
  __syncthreads();

  // carry over previous chunks (lane = h)
  const int h = lane;
  const float Lr = lamtab[128 + h], Li = lamtab[192 + h];
  const float lr = lamtab[h],       li = lamtab[64 + h];
  float cr = 0.f, ci = 0.f;
  const float* Eb = E + (size_t)b * NC * 128;
  for (int cp = 0; cp < c; ++cp) {
    float er = Eb[cp * 128 + h], ei = Eb[cp * 128 + 64 + h];
    float nr = Lr * cr - Li * ci + er;
    ci = Lr * ci + Li * cr + ei;
    cr = nr;
  }
  // correction: xs[l][h] = loc[l][h] + lam^{l+1} * carry ; write bf16 A-frag LDS
  {
    float wr2 = cr, wi2 = ci;
    short* xa = &xsA[w][0];
    const short* zs = &Zs[w][0];
    const int ure = h >> 3, uim = 8 + (h >> 3), ho = h & 7;
    #pragma unroll 4
    for (int l = 0; l < CS; ++l) {
      float nr = lr * wr2 - li * wi2;
      wi2 = lr * wi2 + li * wr2;
      wr2 = nr;
      unsigned pr = *(const unsigned*)&zs[l * WN + 2 * h];
      float xr = bf2f((short)(pr & 0xffff)) + wr2;
      float xi = bf2f((short)(pr >> 16))    + wi2;
      int l7 = l & 7;
      xa[l * 128 + ((ure & ~7) | ((ure ^ l7) & 7)) * 8 + ho] = f2bf(xr);
      xa[l * 128 + ((uim & ~7) | ((uim ^ l7) & 7)) * 8 + ho] = f2bf(xi);
    }
  }
  __syncthreads();

  // MFMA projection: y(32x64) = [xs_re|xs_im](32x128) @ Ctp(128x64)
  const int cc = lane & 31, kh = lane >> 5;
  f32x16 y0, y1;
  #pragma unroll
  for (int j = 0; j < 16; ++j) { y0[j] = 0.f; y1[j] = 0.f; }
  #pragma unroll
  for (int ks = 0; ks < 8; ++ks) {
    int u = ks * 2 + kh;
    int up = (u & ~7) | ((u ^ (cc & 7)) & 7);
    short8 af = *(const short8*)&xsA[w][cc * 128 + up * 8];
    short8 g0 = *(const short8*)(Ctp + ((size_t)((0 * 8 + ks) * 64 + lane)) * 8);
    short8 g1 = *(const short8*)(Ctp + ((size_t)((1 * 8 + ks) * 64 + lane)) * 8);
    y0 = __builtin_amdgcn_mfma_f32_32x32x16_bf16(af, g0, y0, 0, 0, 0);
    y1 = __builtin_amdgcn_mfma_f32_32x32x16_bf16(af, g1, y1, 0, 0, 0);
  }
  // Du add + max over rows
  float mv0 = -3.4e38f, mv1 = -3.4e38f;
  #pragma unroll
  for (int reg = 0; reg < 16; ++reg) {
    const int row = (reg & 3) + 8 * (reg >> 2) + 4 * kh;
    unsigned pd = *(const unsigned*)&Zs[w][row * WN + 128 + 2 * cc];
    mv0 = fmaxf(mv0, y0[reg] + bf2f((short)(pd & 0xffff)));
    mv1 = fmaxf(mv1, y1[reg] + bf2f((short)(pd >> 16)));
  }
  mv0 = fmaxf(mv0, __shfl_xor(mv0, 32));
  mv1 = fmaxf(mv1, __shfl_xor(mv1, 32));
  if (kh == 0) {
    float* Pp = P + ((size_t)b * NC + c) * 64;
    Pp[cc] = mv0;
    Pp[32 + cc] = mv1;
  }
}

// ---------------- K5: max over chunks ----------------
__global__ void k5_reduce(const float* __restrict__ P, float* __restrict__ out) {
  int idx = blockIdx.x * 256 + threadIdx.x;      // = b*64 + o
  int b = idx >> 6, o = idx & 63;
  float m = -3.4e38f;
  for (int c = 0; c < NC; ++c) m = fmaxf(m, P[((size_t)b * NC + c) * 64 + o]);
  out[idx] = m;
}

extern "C" void kernel_launch(void* const* d_in, const int* in_sizes, int n_in,
                              void* d_out, int out_size, void* d_ws, size_t ws_size,
                              hipStream_t stream) {
  const float* X         = (const float*)d_in[0];
  const float* nu_log    = (const float*)d_in[1];
  const float* theta_log = (const float*)d_in[2];
  const float* gamma_log = (const float*)d_in[3];
  const float* B_re      = (const float*)d_in[4];
  const float* B_im      = (const float*)d_in[5];
  const float* C_re      = (const float*)d_in[6];
  const float* C_im      = (const float*)d_in[7];
  const float* Dm        = (const float*)d_in[8];
  float* out = (float*)d_out;

  char* ws = (char*)d_ws;
  short* Wp     = (short*)ws;                       // 147456 B
  short* Ctp    = (short*)(ws + 147456);            // 16384 B
  float* lamtab = (float*)(ws + 163840);            // 1024 B
  short* Z      = (short*)(ws + 165888);            // 25165824 B
  float* E      = (float*)(ws + 165888 + 25165824); // 1048576 B
  float* P      = (float*)(ws + 165888 + 25165824 + 1048576); // 524288 B

  k0_prep<<<64, 256, 0, stream>>>(nu_log, theta_log, gamma_log, B_re, B_im,
                                  C_re, C_im, Dm, Wp, Ctp, lamtab);
  k1_gemm_scan<<<1024, 128, 0, stream>>>(X, Wp, lamtab, Z, E);
  k4_scanproj<<<512, 256, 0, stream>>>(Z, lamtab, E, Ctp, P);
  k5_reduce<<<8, 256, 0, stream>>>(P, out);
}

// Round 5
// 72.152 us; speedup vs baseline: 1.3495x; 1.3495x over previous
//
#include <hip/hip_runtime.h>
#include <hip/hip_bf16.h>

#define B_   32
#define L_   2048
#define DIN  384
#define DH   64
#define DOUT 64
#define CS   32      // chunk length
#define NC   64      // chunks per sequence
#define WN   192     // Z row: shorts [0..127]=(re,im) pairs h=0..63; [128..191]=(Du_c,Du_{c+32}) pairs c=0..31

typedef __attribute__((ext_vector_type(8)))  short short8;
typedef __attribute__((ext_vector_type(4)))  float f32x4;
typedef __attribute__((ext_vector_type(16))) float f32x16;

__device__ __forceinline__ float bf2f(short s) {
  union { unsigned u; float f; } cv;
  cv.u = ((unsigned)(unsigned short)s) << 16;
  return cv.f;
}
__device__ __forceinline__ short f2bf(float f) {
  __hip_bfloat16 h = __float2bfloat16(f);
  union { __hip_bfloat16 h; short s; } cv; cv.h = h;
  return cv.s;
}
__device__ __forceinline__ unsigned pack2(float lo, float hi) {
  return (unsigned)(unsigned short)f2bf(lo) | ((unsigned)(unsigned short)f2bf(hi) << 16);
}

// ---------------- K0: pack Wp (B-frag order), Ctp (proj B-frag order), lamtab ----
__global__ void k0_prep(const float* __restrict__ nu_log, const float* __restrict__ theta_log,
                        const float* __restrict__ gamma_log,
                        const float* __restrict__ B_re, const float* __restrict__ B_im,
                        const float* __restrict__ C_re, const float* __restrict__ C_im,
                        const float* __restrict__ Dm,
                        short* __restrict__ Wp, short* __restrict__ Ctp,
                        float* __restrict__ lamtab) {
  int tid = blockIdx.x * 256 + threadIdx.x;
  // Wp[((nt*24+ks)*64+l)*8+j] = W[nt*32+(l&31)][ks*16+(l>>5)*8+j]
  for (int q = tid; q < 6 * 24 * 64; q += gridDim.x * 256) {
    int l = q & 63, ks = (q >> 6) % 24, nt = q / (24 * 64);
    int n = nt * 32 + (l & 31);
    int k0 = ks * 16 + ((l >> 5) << 3);
    short8 v;
    #pragma unroll
    for (int j = 0; j < 8; ++j) {
      int k = k0 + j;
      float x;
      if (n < 64)       x = B_re[n * DIN + k] * expf(gamma_log[n]);
      else if (n < 128) x = B_im[(n - 64) * DIN + k] * expf(gamma_log[n - 64]);
      else              x = Dm[(n - 128) * DIN + k];
      v[j] = f2bf(x);
    }
    *(short8*)(Wp + (size_t)q * 8) = v;
  }
  // Ctp[((nt2*8+ks2)*64+l)*8+j]: B[k][o], k<64 -> C_re[o][k], k>=64 -> -C_im[o][k-64]
  for (int q = tid; q < 2 * 8 * 64; q += gridDim.x * 256) {
    int l = q & 63, ks2 = (q >> 6) & 7, nt2 = q >> 9;
    int o = nt2 * 32 + (l & 31);
    int kk0 = ks2 * 16 + ((l >> 5) << 3);
    short8 v;
    #pragma unroll
    for (int j = 0; j < 8; ++j) {
      int k = kk0 + j;
      float x = (k < 64) ? C_re[o * DH + k] : -C_im[o * DH + (k - 64)];
      v[j] = f2bf(x);
    }
    *(short8*)(Ctp + (size_t)q * 8) = v;
  }
  if (blockIdx.x == 0 && threadIdx.x < 64) {
    int h = threadIdx.x;
    float nu = expf(nu_log[h]);
    float th = expf(theta_log[h]);
    float rr = expf(-nu);
    float lr = rr * cosf(th), li = rr * sinf(th);
    float ar = lr, ai = li;
    #pragma unroll
    for (int q = 0; q < 5; ++q) { float nr = ar * ar - ai * ai; ai = 2.f * ar * ai; ar = nr; }
    lamtab[h] = lr; lamtab[64 + h] = li;        // lambda
    lamtab[128 + h] = ar; lamtab[192 + h] = ai; // lambda^32
  }
}

// ---- K1: 3 waves per 32-row chunk. Wave 0: nt{0,2} (re/im h=0..31) + scan;
//      wave 1: nt{1,3} (h=32..63) + scan; wave 2: nt{4,5} (Du pairs). ----
__global__ __launch_bounds__(192, 4) void k1_gemm_scan(const float* __restrict__ X,
                                                       const short* __restrict__ Wp,
                                                       const float* __restrict__ lamtab,
                                                       short* __restrict__ Z,
                                                       float* __restrict__ E) {
  __shared__ short Xs[32 * 384];                 // 24 KB, XOR-swizzled on 8-elem units
  const int t = threadIdx.x, w = t / 64, lane = t & 63;
  const int m0 = blockIdx.x * 32;                // 32 rows = 1 chunk

  // ---- stage X tile: fp32 -> bf16 -> swizzled LDS (coalesced)
  #pragma unroll
  for (int it = 0; it < 8; ++it) {
    int q8 = it * 192 + t;                       // 8-elem unit id, 0..1535
    int r = q8 / 48, u = q8 - r * 48;
    const float* src = X + (size_t)(m0 + r) * DIN + u * 8;
    f32x4 a0 = *(const f32x4*)src;
    f32x4 a1 = *(const f32x4*)(src + 4);
    short8 v;
    #pragma unroll
    for (int i = 0; i < 4; ++i) { v[i] = f2bf(a0[i]); v[4 + i] = f2bf(a1[i]); }
    int up = (u & ~7) | ((u ^ r) & 7);
    *(short8*)&Xs[r * 384 + up * 8] = v;
  }
  __syncthreads();

  const int c = lane & 31, kh = lane >> 5;
  const short* xrow = &Xs[c * 384];
  const int ntx = (w < 2) ? w : 4;
  const int nty = (w < 2) ? w + 2 : 5;
  const short* wqx = Wp + (size_t)ntx * 12288 + lane * 8;
  const short* wqy = Wp + (size_t)nty * 12288 + lane * 8;

  f32x16 accx, accy;
  #pragma unroll
  for (int j = 0; j < 16; ++j) { accx[j] = 0.f; accy[j] = 0.f; }

#define AREAD(KS) (*(const short8*)&xrow[(((((KS)*2 + kh)) & ~7) | ((((KS)*2 + kh) ^ c) & 7)) * 8])

  short8 a0 = AREAD(0), a1 = AREAD(1);
  short8 bx0 = *(const short8*)(wqx + 0 * 512);
  short8 by0 = *(const short8*)(wqy + 0 * 512);
  short8 bx1 = *(const short8*)(wqx + 1 * 512);
  short8 by1 = *(const short8*)(wqy + 1 * 512);
  short8 bx2 = *(const short8*)(wqx + 2 * 512);
  short8 by2 = *(const short8*)(wqy + 2 * 512);

  #pragma unroll
  for (int ks = 0; ks < 24; ++ks) {
    short8 a_n, bxn, byn;
    if (ks < 22) a_n = AREAD(ks + 2);
    if (ks < 21) {
      bxn = *(const short8*)(wqx + (ks + 3) * 512);
      byn = *(const short8*)(wqy + (ks + 3) * 512);
    }
    accx = __builtin_amdgcn_mfma_f32_32x32x16_bf16(a0, bx0, accx, 0, 0, 0);
    accy = __builtin_amdgcn_mfma_f32_32x32x16_bf16(a0, by0, accy, 0, 0, 0);
    a0 = a1; a1 = a_n;
    bx0 = bx1; bx1 = bx2; bx2 = bxn;
    by0 = by1; by1 = by2; by2 = byn;
  }
#undef AREAD

  // ---- in-register local scan (waves 0,1 only); lane scans h = w*32 + c
  float sr = 0.f, si = 0.f;
  if (w < 2) {
    const float lr = lamtab[w * 32 + c], li = lamtab[64 + w * 32 + c];
    #pragma unroll
    for (int g = 0; g < 8; ++g) {
      const int active = (g & 1);
      if (kh == active) {
        #pragma unroll
        for (int j = 0; j < 4; ++j) {
          const int r = 4 * (g >> 1) + j;
          float nr = lr * sr - li * si + accx[r];
          si = lr * si + li * sr + accy[r];
          sr = nr;
          accx[r] = sr; accy[r] = si;
        }
      }
      float tr = __shfl_xor(sr, 32), ti = __shfl_xor(si, 32);
      if (kh != active) { sr = tr; si = ti; }
    }
  }

  // ---- store Z: waves 0/1 -> (re,im) pairs at col off w*64; wave 2 -> Du pairs at 128
  const int zo = (w < 2) ? w * 64 : 128;
  #pragma unroll
  for (int reg = 0; reg < 16; ++reg) {
    const int row = (reg & 3) + 8 * (reg >> 2) + 4 * kh;
    *(unsigned*)(Z + (size_t)(m0 + row) * WN + zo + 2 * c) = pack2(accx[reg], accy[reg]);
  }
  if (w < 2 && kh == 0) {
    float* Ep = E + (size_t)blockIdx.x * 128;
    Ep[w * 32 + c] = sr;
    Ep[64 + w * 32 + c] = si;
  }
}

// ---- K4: carry + correction + MFMA projection + Du + chunk max (no barriers) ----
__global__ __launch_bounds__(256, 4) void k4_scanproj(const short* __restrict__ Z,
                                                      const float* __restrict__ lamtab,
                                                      const float* __restrict__ E,
                                                      const short* __restrict__ Ctp,
                                                      float* __restrict__ P) {
  const int t = threadIdx.x, w = t >> 6, lane = t & 63;
  const int b = blockIdx.x >> 4, cg = blockIdx.x & 15;
  const int c = cg * 4 + w;                      // this wave's chunk
  __shared__ short xsA[4][CS * 128];             // 32 KB, swizzled A-frag layout
  const size_t zrow0 = (size_t)(b * L_ + c * CS) * WN;

  // carry over previous chunks (lane = h)
  const int h = lane;
  const float Lr = lamtab[128 + h], Li = lamtab[192 + h];
  const float lr = lamtab[h],       li = lamtab[64 + h];
  float cr = 0.f, ci = 0.f;
  const float* Eb = E + (size_t)b * NC * 128;
  for (int cp = 0; cp < c; ++cp) {
    float er = Eb[cp * 128 + h], ei = Eb[cp * 128 + 64 + h];
    float nr = Lr * cr - Li * ci + er;
    ci = Lr * ci + Li * cr + ei;
    cr = nr;
  }
  // correction: xs[l][h] = loc[l][h] + lam^{l+1} * carry ; write bf16 A-frag LDS
  {
    float wr2 = cr, wi2 = ci;
    short* xa = &xsA[w][0];
    const int ure = h >> 3, uim = 8 + (h >> 3), ho = h & 7;
    #pragma unroll 8
    for (int l = 0; l < CS; ++l) {
      float nr = lr * wr2 - li * wi2;
      wi2 = lr * wi2 + li * wr2;
      wr2 = nr;
      unsigned pr = *(const unsigned*)(Z + zrow0 + (size_t)l * WN + 2 * h);
      float xr = bf2f((short)(pr & 0xffff)) + wr2;
      float xi = bf2f((short)(pr >> 16))    + wi2;
      int l7 = l & 7;
      xa[l * 128 + ((ure & ~7) | ((ure ^ l7) & 7)) * 8 + ho] = f2bf(xr);
      xa[l * 128 + ((uim & ~7) | ((uim ^ l7) & 7)) * 8 + ho] = f2bf(xi);
    }
  }

  // MFMA projection: y(32x64) = [xs_re|xs_im](32x128) @ Ctp(128x64)
  const int cc = lane & 31, kh = lane >> 5;
  f32x16 y0, y1;
  #pragma unroll
  for (int j = 0; j < 16; ++j) { y0[j] = 0.f; y1[j] = 0.f; }
  #pragma unroll
  for (int ks = 0; ks < 8; ++ks) {
    int u = ks * 2 + kh;
    int up = (u & ~7) | ((u ^ (cc & 7)) & 7);
    short8 af = *(const short8*)&xsA[w][cc * 128 + up * 8];
    short8 g0 = *(const short8*)(Ctp + ((size_t)((0 * 8 + ks) * 64 + lane)) * 8);
    short8 g1 = *(const short8*)(Ctp + ((size_t)((1 * 8 + ks) * 64 + lane)) * 8);
    y0 = __builtin_amdgcn_mfma_f32_32x32x16_bf16(af, g0, y0, 0, 0, 0);
    y1 = __builtin_amdgcn_mfma_f32_32x32x16_bf16(af, g1, y1, 0, 0, 0);
  }
  // Du add + max over rows
  float mv0 = -3.4e38f, mv1 = -3.4e38f;
  #pragma unroll
  for (int reg = 0; reg < 16; ++reg) {
    const int row = (reg & 3) + 8 * (reg >> 2) + 4 * kh;
    unsigned pd = *(const unsigned*)(Z + zrow0 + (size_t)row * WN + 128 + 2 * cc);
    mv0 = fmaxf(mv0, y0[reg] + bf2f((short)(pd & 0xffff)));
    mv1 = fmaxf(mv1, y1[reg] + bf2f((short)(pd >> 16)));
  }
  mv0 = fmaxf(mv0, __shfl_xor(mv0, 32));
  mv1 = fmaxf(mv1, __shfl_xor(mv1, 32));
  if (kh == 0) {
    float* Pp = P + ((size_t)b * NC + c) * 64;
    Pp[cc] = mv0;
    Pp[32 + cc] = mv1;
  }
}

// ---------------- K5: max over chunks ----------------
__global__ void k5_reduce(const float* __restrict__ P, float* __restrict__ out) {
  int idx = blockIdx.x * 256 + threadIdx.x;      // = b*64 + o
  int b = idx >> 6, o = idx & 63;
  float m = -3.4e38f;
  for (int c = 0; c < NC; ++c) m = fmaxf(m, P[((size_t)b * NC + c) * 64 + o]);
  out[idx] = m;
}

extern "C" void kernel_launch(void* const* d_in, const int* in_sizes, int n_in,
                              void* d_out, int out_size, void* d_ws, size_t ws_size,
                              hipStream_t stream) {
  const float* X         = (const float*)d_in[0];
  const float* nu_log    = (const float*)d_in[1];
  const float* theta_log = (const float*)d_in[2];
  const float* gamma_log = (const float*)d_in[3];
  const float* B_re      = (const float*)d_in[4];
  const float* B_im      = (const float*)d_in[5];
  const float* C_re      = (const float*)d_in[6];
  const float* C_im      = (const float*)d_in[7];
  const float* Dm        = (const float*)d_in[8];
  float* out = (float*)d_out;

  char* ws = (char*)d_ws;
  short* Wp     = (short*)ws;                       // 147456 B
  short* Ctp    = (short*)(ws + 147456);            // 16384 B
  float* lamtab = (float*)(ws + 163840);            // 1024 B
  short* Z      = (short*)(ws + 165888);            // 25165824 B
  float* E      = (float*)(ws + 165888 + 25165824); // 1048576 B
  float* P      = (float*)(ws + 165888 + 25165824 + 1048576); // 524288 B

  k0_prep<<<64, 256, 0, stream>>>(nu_log, theta_log, gamma_log, B_re, B_im,
                                  C_re, C_im, Dm, Wp, Ctp, lamtab);
  k1_gemm_scan<<<2048, 192, 0, stream>>>(X, Wp, lamtab, Z, E);
  k4_scanproj<<<512, 256, 0, stream>>>(Z, lamtab, E, Ctp, P);
  k5_reduce<<<8, 256, 0, stream>>>(P, out);
}